// Round 4
// baseline (126.261 us; speedup 1.0000x reference)
//
#include <hip/hip_runtime.h>
#include <cstdint>
#include <cstddef>

#define BATCH 2
#define NVIEW 6
#define MTOK  1369
#define DIM   384
#define VOXPB 65536
#define PFEAT 64
#define HID   256
#define OUTD  16
#define GRIDN 37

typedef float  f32x4  __attribute__((ext_vector_type(4)));
typedef short  bf16x8 __attribute__((ext_vector_type(8)));
typedef _Float16 f16x4 __attribute__((ext_vector_type(4)));

// ---- workspace layout (bytes) ----
#define OFF_T    0
#define SZ_T     (BATCH*MTOK*HID*2)          // T swizzled: flat short s*16+nt = T[t][nt*16+s]
#define OFF_W1B  (OFF_T + SZ_T)
#define SZ_W1B   (DIM*HID*2)                 // W1b B-frags bf16
#define OFF_W1A  (OFF_W1B + SZ_W1B)
#define SZ_W1A   (PFEAT*HID*2)               // W1a frags bf16 (A-frag of W1a^T == B-frag of W1a)
#define OFF_W2T  (OFF_W1A + SZ_W1A)
#define SZ_W2T   (HID*OUTD*2)                // W2^T A-frags f16

__device__ __forceinline__ unsigned short f2bf(float x) {
    unsigned u = __float_as_uint(x);
    unsigned r = (u + 0x7FFFu + ((u >> 16) & 1u)) >> 16;   // RNE to bf16
    return (unsigned short)r;
}

// ============================================================================
// Kernel 1: weight fragment pre-swizzle
// ============================================================================
#define W1B_BLKS   384
#define W1A_BLKS   64
#define W2T_BLKS   16

__global__ __launch_bounds__(256) void prep_kernel(
    const float* __restrict__ W1, const float* __restrict__ W2,
    unsigned short* __restrict__ ws16)
{
    int blk = blockIdx.x;
    if (blk < W1B_BLKS) {   // B-frag 16x16x32: n=lane&15, k=(lane>>4)*8+j
        int e = blk*256 + threadIdx.x;
        int j = e & 7, lane = (e >> 3) & 63, nt = (e >> 9) & 15, kc = e >> 13;
        int k = kc*32 + (lane >> 4)*8 + j;
        int n = nt*16 + (lane & 15);
        ws16[OFF_W1B/2 + e] = f2bf(W1[(PFEAT + k)*HID + n]);
        return;
    }
    blk -= W1B_BLKS;
    if (blk < W1A_BLKS) {   // same bytes serve as A-frag of W1a^T (m=lane&15=hid, k=(lane>>4)*8+j)
        int e = blk*256 + threadIdx.x;
        int j = e & 7, lane = (e >> 3) & 63, nt = (e >> 9) & 15, kc = e >> 13;
        int k = kc*32 + (lane >> 4)*8 + j;
        int n = nt*16 + (lane & 15);
        ws16[OFF_W1A/2 + e] = f2bf(W1[k*HID + n]);
        return;
    }
    blk -= W1A_BLKS;
    {   // W2^T A-frags 16x16x16 f16: A[m=lane&15][k=(lane>>4)*4+j + nt*16]
        int e = blk*256 + threadIdx.x;
        int j = e & 3, lane = (e >> 2) & 63, nt = e >> 8;
        int k = nt*16 + (lane >> 4)*4 + j;
        _Float16 v = (_Float16)W2[k*OUTD + (lane & 15)];
        ws16[OFF_W2T/2 + e] = __builtin_bit_cast(unsigned short, v);
    }
}

// ============================================================================
// Kernel 2: T_sw = swizzle(b1 + mean_views(patch) @ W1b)
// ============================================================================
#define T_ROWS (BATCH*MTOK)                  // 2738
#define TM     16
#define T_BLKS ((T_ROWS + TM - 1)/TM)        // 172
#define APAD   392

__global__ __launch_bounds__(256) void t_gemm_kernel(
    const float* __restrict__ patch, const unsigned short* __restrict__ ws16r,
    const float* __restrict__ b1, unsigned short* __restrict__ ws16)
{
    __shared__ unsigned short Abuf[TM*APAD];
    const int tid = threadIdx.x;
    const int tileBase = blockIdx.x*TM;

    #pragma unroll
    for (int it = 0; it < 6; it++) {
        int i = it*256 + tid;                  // < 1536
        int row = i / 96, c = i - row*96;
        int gr = tileBase + row;
        f32x4 s = {0.f,0.f,0.f,0.f};
        if (gr < T_ROWS) {
            int b = (gr >= MTOK) ? 1 : 0;
            int m = gr - b*MTOK;
            const float* p = patch + (((size_t)(b*NVIEW))*MTOK + m)*DIM + c*4;
            #pragma unroll
            for (int nv = 0; nv < NVIEW; nv++)
                s += *(const f32x4*)(p + (size_t)nv*MTOK*DIM);
            s *= (1.0f/6.0f);
        }
        ushort4 pk;
        pk.x = f2bf(s[0]); pk.y = f2bf(s[1]); pk.z = f2bf(s[2]); pk.w = f2bf(s[3]);
        *(ushort4*)(Abuf + row*APAD + c*4) = pk;
    }
    __syncthreads();

    const int lane = tid & 63, wv = tid >> 6;
    const int q = lane >> 4, l = lane & 15;
    const uint4* bfr = (const uint4*)(ws16r + OFF_W1B/2);

    f32x4 acc[4];
    #pragma unroll
    for (int a = 0; a < 4; a++) acc[a] = (f32x4){0.f,0.f,0.f,0.f};

    #pragma unroll 4
    for (int kc = 0; kc < 12; kc++) {
        const bf16x8 af = *(const bf16x8*)(Abuf + l*APAD + kc*32 + q*8);
        #pragma unroll
        for (int ntl = 0; ntl < 4; ntl++) {
            bf16x8 bfrag = __builtin_bit_cast(bf16x8, bfr[(kc*16 + wv*4 + ntl)*64 + lane]);
            acc[ntl] = __builtin_amdgcn_mfma_f32_16x16x32_bf16(af, bfrag, acc[ntl], 0, 0, 0);
        }
    }

    // epilogue: flat short index s*16+nt with s=l, nt=wv*4+ntl
    unsigned short* T = ws16 + OFF_T/2;
    float bbv[4];
    #pragma unroll
    for (int ntl = 0; ntl < 4; ntl++) bbv[ntl] = b1[(wv*4 + ntl)*16 + l];
    #pragma unroll
    for (int r = 0; r < 4; r++) {
        int row = tileBase + q*4 + r;
        if (row < T_ROWS) {
            ushort4 pk;
            pk.x = f2bf(acc[0][r] + bbv[0]);
            pk.y = f2bf(acc[1][r] + bbv[1]);
            pk.z = f2bf(acc[2][r] + bbv[2]);
            pk.w = f2bf(acc[3][r] + bbv[3]);
            *(ushort4*)(T + (size_t)row*HID + l*16 + wv*4) = pk;
        }
    }
}

// ============================================================================
// Kernel 3: projection + FC1 (D = W1a^T x vf -> vox-on-lane) + relu+T
//           + FC2 directly (no transpose MFMA); 2048 blocks, 16 vox/wave
// ============================================================================
__device__ __forceinline__ int proj_idx(float x, float y, float z,
                                        const float* __restrict__ Km,
                                        const float* __restrict__ Rt)
{
    float c0 = __fadd_rn(__fadd_rn(__fadd_rn(__fmul_rn(Rt[0],x), __fmul_rn(Rt[1],y)), __fmul_rn(Rt[2],z)), Rt[3]);
    float c1 = __fadd_rn(__fadd_rn(__fadd_rn(__fmul_rn(Rt[4],x), __fmul_rn(Rt[5],y)), __fmul_rn(Rt[6],z)), Rt[7]);
    float c2 = __fadd_rn(__fadd_rn(__fadd_rn(__fmul_rn(Rt[8],x), __fmul_rn(Rt[9],y)), __fmul_rn(Rt[10],z)), Rt[11]);
    float p0 = __fadd_rn(__fadd_rn(__fmul_rn(Km[0],c0), __fmul_rn(Km[1],c1)), __fmul_rn(Km[2],c2));
    float p1 = __fadd_rn(__fadd_rn(__fmul_rn(Km[3],c0), __fmul_rn(Km[4],c1)), __fmul_rn(Km[5],c2));
    float p2 = __fadd_rn(__fadd_rn(__fmul_rn(Km[6],c0), __fmul_rn(Km[7],c1)), __fmul_rn(Km[8],c2));
    float zz = __fadd_rn(p2, 1e-6f);
    float u  = __fmul_rn(__fdiv_rn(p0, zz), 518.0f/600.0f);
    float v  = __fmul_rn(__fdiv_rn(p1, zz), 518.0f/900.0f);
    float fu = __fdiv_rn(u, 14.0f);
    float fv = __fdiv_rn(v, 14.0f);
    int px = (__builtin_fabsf(fu) < 2147483648.0f) ? (int)fu : (int)0x80000000;
    int py = (__builtin_fabsf(fv) < 2147483648.0f) ? (int)fv : (int)0x80000000;
    px = min(max(px, 0), GRIDN-1);
    py = min(max(py, 0), GRIDN-1);
    return px*GRIDN + py;
}

__global__ __launch_bounds__(256, 4) void main_kernel(
    const float* __restrict__ vf, const float* __restrict__ coords,
    const float* __restrict__ Km, const float* __restrict__ Rt,
    const unsigned short* __restrict__ ws16, const float* __restrict__ b2,
    float* __restrict__ out)
{
    __shared__ uint4 w1aS[2048];     // 32 KB W1a frags
    __shared__ int   idxS[64];

    const int tid = threadIdx.x;
    const int lane = tid & 63, wv = tid >> 6;
    const int q = lane >> 4, l = lane & 15;
    const int voxG = blockIdx.x*64 + wv*16;        // 16 voxels per wave
    const int b = blockIdx.x >> 10;                // 1024 blocks per batch

    // issue independent global loads before the barrier
    const uint4* w1aG = (const uint4*)(ws16 + OFF_W1A/2);
    #pragma unroll
    for (int i = 0; i < 8; i++) w1aS[i*256 + tid] = w1aG[i*256 + tid];

    // vf as FC1 B-operand: lane(q,l) holds vf[voxG+l][kc*32+q*8+j]
    bf16x8 a1[2];
    {
        const float* vp = vf + (size_t)(voxG + l)*PFEAT;
        #pragma unroll
        for (int kc = 0; kc < 2; kc++) {
            const float* pp = vp + kc*32 + q*8;
            f32x4 v0 = *(const f32x4*)pp;
            f32x4 v1 = *(const f32x4*)(pp + 4);
            bf16x8 f;
            f[0]=f2bf(v0[0]); f[1]=f2bf(v0[1]); f[2]=f2bf(v0[2]); f[3]=f2bf(v0[3]);
            f[4]=f2bf(v1[0]); f[5]=f2bf(v1[1]); f[6]=f2bf(v1[2]); f[7]=f2bf(v1[3]);
            a1[kc] = f;
        }
    }

    if (tid < 64) {
        int vox = blockIdx.x*64 + tid;
        const float* cp = coords + (size_t)vox*3;
        idxS[tid] = proj_idx(cp[0], cp[1], cp[2], Km, Rt);
    }
    __syncthreads();

    // per-lane T row (own voxel), contiguous 128 B at offset q*128
    // flat short r*16+nt (local) = T[row][nt*16 + q*4 + r]
    const unsigned short* T = ws16 + OFF_T/2;
    uint4 tra[4][2];
    {
        int row = b*MTOK + idxS[wv*16 + l];
        const uint4* tp = (const uint4*)(T + (size_t)row*HID + q*64);
        #pragma unroll
        for (int r = 0; r < 4; r++) {
            tra[r][0] = tp[r*2];
            tra[r][1] = tp[r*2 + 1];
        }
    }

    const unsigned short* w2tG = ws16 + OFF_W2T/2;
    const f32x4 zero4 = {0.f,0.f,0.f,0.f};
    f32x4 acc2 = zero4;

    #pragma unroll
    for (int nt = 0; nt < 16; nt++) {
        bf16x8 wf0 = __builtin_bit_cast(bf16x8, w1aS[nt*64 + lane]);
        bf16x8 wf1 = __builtin_bit_cast(bf16x8, w1aS[(16 + nt)*64 + lane]);
        f16x4 w2t = *(const f16x4*)(w2tG + (nt*64 + lane)*4);  // L2 hit
        // FC1: D[hid nt*16+q*4+r][vox l]
        f32x4 d1 = __builtin_amdgcn_mfma_f32_16x16x32_bf16(wf0, a1[0], zero4, 0, 0, 0);
        d1       = __builtin_amdgcn_mfma_f32_16x16x32_bf16(wf1, a1[1], d1,    0, 0, 0);
        // h^T fragment is directly FC2's B-operand layout
        f16x4 hb;
        #pragma unroll
        for (int r = 0; r < 4; r++) {
            unsigned dw = ((const unsigned*)&tra[r])[nt >> 1];
            float tval = (nt & 1) ? __uint_as_float(dw & 0xFFFF0000u)
                                  : __uint_as_float(dw << 16);
            hb[r] = (_Float16)fmaxf(d1[r] + tval, 0.0f);
        }
        acc2 = __builtin_amdgcn_mfma_f32_16x16x16f16(w2t, hb, acc2, 0, 0, 0);
    }

    // epilogue: D[out q*4+r][vox l]
    f32x4 bb = *(const f32x4*)(b2 + q*4);
    f32x4 o = acc2 + bb;
    *(f32x4*)(out + (size_t)(voxG + l)*OUTD + q*4) = o;
}

// ============================================================================
extern "C" void kernel_launch(void* const* d_in, const int* in_sizes, int n_in,
                              void* d_out, int out_size, void* d_ws, size_t ws_size,
                              hipStream_t stream)
{
    const float* patch  = (const float*)d_in[0];
    const float* vfeat  = (const float*)d_in[1];
    const float* coords = (const float*)d_in[2];
    const float* Km     = (const float*)d_in[3];
    const float* Rt     = (const float*)d_in[4];
    const float* W1     = (const float*)d_in[5];
    const float* b1     = (const float*)d_in[6];
    const float* W2     = (const float*)d_in[7];
    const float* b2     = (const float*)d_in[8];
    float* out          = (float*)d_out;
    unsigned short* ws16 = (unsigned short*)d_ws;

    const int prepBlocks = W1B_BLKS + W1A_BLKS + W2T_BLKS;   // 464
    prep_kernel<<<prepBlocks, 256, 0, stream>>>(W1, W2, ws16);
    t_gemm_kernel<<<T_BLKS, 256, 0, stream>>>(patch, ws16, b1, ws16);
    main_kernel<<<(BATCH*VOXPB)/64, 256, 0, stream>>>(vfeat, coords, Km, Rt,
                                                      ws16, b2, out);
}

// Round 5
// 123.202 us; speedup vs baseline: 1.0248x; 1.0248x over previous
//
#include <hip/hip_runtime.h>
#include <cstdint>
#include <cstddef>

#define BATCH 2
#define NVIEW 6
#define MTOK  1369
#define DIM   384
#define VOXPB 65536
#define PFEAT 64
#define HID   256
#define OUTD  16
#define GRIDN 37

typedef float  f32x4  __attribute__((ext_vector_type(4)));
typedef short  bf16x8 __attribute__((ext_vector_type(8)));
typedef _Float16 f16x4 __attribute__((ext_vector_type(4)));

// ---- workspace layout (bytes) ----
#define OFF_T    0
#define SZ_T     (BATCH*MTOK*HID*2)          // T swizzled: flat short s*16+nt = T[t][nt*16+s]
#define OFF_W1B  (OFF_T + SZ_T)
#define SZ_W1B   (DIM*HID*2)                 // W1b B-frags bf16
#define OFF_W1A  (OFF_W1B + SZ_W1B)
#define SZ_W1A   (PFEAT*HID*2)               // W1a frags bf16 (A-frag of W1a^T == B-frag of W1a)
#define OFF_W2T  (OFF_W1A + SZ_W1A)
#define SZ_W2T   (HID*OUTD*2)                // W2^T A-frags f16

__device__ __forceinline__ unsigned short f2bf(float x) {
    unsigned u = __float_as_uint(x);
    unsigned r = (u + 0x7FFFu + ((u >> 16) & 1u)) >> 16;   // RNE to bf16
    return (unsigned short)r;
}

// ============================================================================
// Kernel 1: weight fragment pre-swizzle (vectorized: 8 shorts/thread)
// ============================================================================
#define W1B_BLKS   48     // 98304 shorts / 8 / 256
#define W1A_BLKS   8      // 16384 / 8 / 256
#define W2T_BLKS   4      // 4096 / 4 / 256

__global__ __launch_bounds__(256) void prep_kernel(
    const float* __restrict__ W1, const float* __restrict__ W2,
    unsigned short* __restrict__ ws16)
{
    int blk = blockIdx.x;
    if (blk < W1B_BLKS) {   // B-frag 16x16x32: frag(kc,nt,lane) j=0..7 -> W1[PFEAT+kc*32+(lane>>4)*8+j][nt*16+(lane&15)]
        int e8 = blk*256 + threadIdx.x;                // frag id, < 12288
        int lane = e8 & 63, nt = (e8 >> 6) & 15, kc = e8 >> 10;
        int k0 = kc*32 + (lane >> 4)*8;
        int n  = nt*16 + (lane & 15);
        const float* src = W1 + (size_t)(PFEAT + k0)*HID + n;
        ushort4 p0, p1;
        p0.x = f2bf(src[0*HID]); p0.y = f2bf(src[1*HID]);
        p0.z = f2bf(src[2*HID]); p0.w = f2bf(src[3*HID]);
        p1.x = f2bf(src[4*HID]); p1.y = f2bf(src[5*HID]);
        p1.z = f2bf(src[6*HID]); p1.w = f2bf(src[7*HID]);
        ushort4* dst = (ushort4*)(ws16 + OFF_W1B/2 + (size_t)e8*8);
        dst[0] = p0; dst[1] = p1;
        return;
    }
    blk -= W1B_BLKS;
    if (blk < W1A_BLKS) {   // same bytes serve as A-frag of W1a^T
        int e8 = blk*256 + threadIdx.x;                // < 2048
        int lane = e8 & 63, nt = (e8 >> 6) & 15, kc = e8 >> 10;
        int k0 = kc*32 + (lane >> 4)*8;
        int n  = nt*16 + (lane & 15);
        const float* src = W1 + (size_t)k0*HID + n;
        ushort4 p0, p1;
        p0.x = f2bf(src[0*HID]); p0.y = f2bf(src[1*HID]);
        p0.z = f2bf(src[2*HID]); p0.w = f2bf(src[3*HID]);
        p1.x = f2bf(src[4*HID]); p1.y = f2bf(src[5*HID]);
        p1.z = f2bf(src[6*HID]); p1.w = f2bf(src[7*HID]);
        ushort4* dst = (ushort4*)(ws16 + OFF_W1A/2 + (size_t)e8*8);
        dst[0] = p0; dst[1] = p1;
        return;
    }
    blk -= W1A_BLKS;
    {   // W2^T A-frags 16x16x16 f16: frag(nt,lane) j=0..3 -> W2[nt*16+(lane>>4)*4+j][lane&15]
        int e4 = blk*256 + threadIdx.x;                // < 1024
        int lane = e4 & 63, nt = e4 >> 6;
        int k0 = nt*16 + (lane >> 4)*4;
        int m  = lane & 15;
        ushort4 p;
        _Float16 v0 = (_Float16)W2[(k0+0)*OUTD + m];
        _Float16 v1 = (_Float16)W2[(k0+1)*OUTD + m];
        _Float16 v2 = (_Float16)W2[(k0+2)*OUTD + m];
        _Float16 v3 = (_Float16)W2[(k0+3)*OUTD + m];
        p.x = __builtin_bit_cast(unsigned short, v0);
        p.y = __builtin_bit_cast(unsigned short, v1);
        p.z = __builtin_bit_cast(unsigned short, v2);
        p.w = __builtin_bit_cast(unsigned short, v3);
        *(ushort4*)(ws16 + OFF_W2T/2 + (size_t)e4*4) = p;
    }
}

// ============================================================================
// Kernel 2: T_sw = swizzle(b1 + mean_views(patch) @ W1b)
//           TM=8 -> 343 blocks (full-chip patch streaming)
// ============================================================================
#define T_ROWS (BATCH*MTOK)                  // 2738
#define TM     8
#define T_BLKS ((T_ROWS + TM - 1)/TM)        // 343
#define APAD   392

__global__ __launch_bounds__(256) void t_gemm_kernel(
    const float* __restrict__ patch, const unsigned short* __restrict__ ws16r,
    const float* __restrict__ b1, unsigned short* __restrict__ ws16)
{
    __shared__ unsigned short Abuf[16*APAD];   // 16 M-rows (8 real + 8 zero)
    const int tid = threadIdx.x;
    const int tileBase = blockIdx.x*TM;

    #pragma unroll
    for (int it = 0; it < 6; it++) {
        int i = it*256 + tid;                  // < 1536 = 16 rows x 96 f32x4-cols
        int row = i / 96, c = i - row*96;
        int gr = tileBase + row;
        f32x4 s = {0.f,0.f,0.f,0.f};
        if (row < TM && gr < T_ROWS) {
            int b = (gr >= MTOK) ? 1 : 0;
            int m = gr - b*MTOK;
            const float* p = patch + (((size_t)(b*NVIEW))*MTOK + m)*DIM + c*4;
            #pragma unroll
            for (int nv = 0; nv < NVIEW; nv++)
                s += *(const f32x4*)(p + (size_t)nv*MTOK*DIM);
            s *= (1.0f/6.0f);
        }
        ushort4 pk;
        pk.x = f2bf(s[0]); pk.y = f2bf(s[1]); pk.z = f2bf(s[2]); pk.w = f2bf(s[3]);
        *(ushort4*)(Abuf + row*APAD + c*4) = pk;
    }
    __syncthreads();

    const int lane = tid & 63, wv = tid >> 6;
    const int q = lane >> 4, l = lane & 15;
    const uint4* bfr = (const uint4*)(ws16r + OFF_W1B/2);

    f32x4 acc[4];
    #pragma unroll
    for (int a = 0; a < 4; a++) acc[a] = (f32x4){0.f,0.f,0.f,0.f};

    #pragma unroll 4
    for (int kc = 0; kc < 12; kc++) {
        const bf16x8 af = *(const bf16x8*)(Abuf + l*APAD + kc*32 + q*8);
        #pragma unroll
        for (int ntl = 0; ntl < 4; ntl++) {
            bf16x8 bfrag = __builtin_bit_cast(bf16x8, bfr[(kc*16 + wv*4 + ntl)*64 + lane]);
            acc[ntl] = __builtin_amdgcn_mfma_f32_16x16x32_bf16(af, bfrag, acc[ntl], 0, 0, 0);
        }
    }

    // epilogue: flat short index s*16+nt with s=l, nt=wv*4+ntl ; D row = q*4+r
    unsigned short* T = ws16 + OFF_T/2;
    float bbv[4];
    #pragma unroll
    for (int ntl = 0; ntl < 4; ntl++) bbv[ntl] = b1[(wv*4 + ntl)*16 + l];
    #pragma unroll
    for (int r = 0; r < 4; r++) {
        int rr = q*4 + r;
        int row = tileBase + rr;
        if (rr < TM && row < T_ROWS) {
            ushort4 pk;
            pk.x = f2bf(acc[0][r] + bbv[0]);
            pk.y = f2bf(acc[1][r] + bbv[1]);
            pk.z = f2bf(acc[2][r] + bbv[2]);
            pk.w = f2bf(acc[3][r] + bbv[3]);
            *(ushort4*)(T + (size_t)row*HID + l*16 + wv*4) = pk;
        }
    }
}

// ============================================================================
// Kernel 3: projection (per-lane) + FC1 (W1a^T x vf, C preloaded with T)
//           + FC2 ; 2048 blocks x 256 thr, 16 vox/wave
// ============================================================================
__device__ __forceinline__ int proj_idx(float x, float y, float z,
                                        const float* __restrict__ Km,
                                        const float* __restrict__ Rt)
{
    float c0 = __fadd_rn(__fadd_rn(__fadd_rn(__fmul_rn(Rt[0],x), __fmul_rn(Rt[1],y)), __fmul_rn(Rt[2],z)), Rt[3]);
    float c1 = __fadd_rn(__fadd_rn(__fadd_rn(__fmul_rn(Rt[4],x), __fmul_rn(Rt[5],y)), __fmul_rn(Rt[6],z)), Rt[7]);
    float c2 = __fadd_rn(__fadd_rn(__fadd_rn(__fmul_rn(Rt[8],x), __fmul_rn(Rt[9],y)), __fmul_rn(Rt[10],z)), Rt[11]);
    float p0 = __fadd_rn(__fadd_rn(__fmul_rn(Km[0],c0), __fmul_rn(Km[1],c1)), __fmul_rn(Km[2],c2));
    float p1 = __fadd_rn(__fadd_rn(__fmul_rn(Km[3],c0), __fmul_rn(Km[4],c1)), __fmul_rn(Km[5],c2));
    float p2 = __fadd_rn(__fadd_rn(__fmul_rn(Km[6],c0), __fmul_rn(Km[7],c1)), __fmul_rn(Km[8],c2));
    float zz = __fadd_rn(p2, 1e-6f);
    float u  = __fmul_rn(__fdiv_rn(p0, zz), 518.0f/600.0f);
    float v  = __fmul_rn(__fdiv_rn(p1, zz), 518.0f/900.0f);
    float fu = __fdiv_rn(u, 14.0f);
    float fv = __fdiv_rn(v, 14.0f);
    int px = (__builtin_fabsf(fu) < 2147483648.0f) ? (int)fu : (int)0x80000000;
    int py = (__builtin_fabsf(fv) < 2147483648.0f) ? (int)fv : (int)0x80000000;
    px = min(max(px, 0), GRIDN-1);
    py = min(max(py, 0), GRIDN-1);
    return px*GRIDN + py;
}

__global__ __launch_bounds__(256, 4) void main_kernel(
    const float* __restrict__ vf, const float* __restrict__ coords,
    const float* __restrict__ Km, const float* __restrict__ Rt,
    const unsigned short* __restrict__ ws16, const float* __restrict__ b2,
    float* __restrict__ out)
{
    __shared__ uint4 w1aS[2048];     // 32 KB W1a frags

    const int tid = threadIdx.x;
    const int lane = tid & 63, wv = tid >> 6;
    const int q = lane >> 4, l = lane & 15;
    const int voxG = blockIdx.x*64 + wv*16;        // 16 voxels per wave
    const int b = blockIdx.x >> 10;                // 1024 blocks per batch

    // stage W1a frags (independent of everything below)
    const uint4* w1aG = (const uint4*)(ws16 + OFF_W1A/2);
    #pragma unroll
    for (int i = 0; i < 8; i++) w1aS[i*256 + tid] = w1aG[i*256 + tid];

    // vf as FC1 B-operand: lane(q,l) holds vf[voxG+l][kc*32+q*8+j]
    bf16x8 a1[2];
    {
        const float* vp = vf + (size_t)(voxG + l)*PFEAT;
        #pragma unroll
        for (int kc = 0; kc < 2; kc++) {
            const float* pp = vp + kc*32 + q*8;
            f32x4 v0 = *(const f32x4*)pp;
            f32x4 v1 = *(const f32x4*)(pp + 4);
            bf16x8 f;
            f[0]=f2bf(v0[0]); f[1]=f2bf(v0[1]); f[2]=f2bf(v0[2]); f[3]=f2bf(v0[3]);
            f[4]=f2bf(v1[0]); f[5]=f2bf(v1[1]); f[6]=f2bf(v1[2]); f[7]=f2bf(v1[3]);
            a1[kc] = f;
        }
    }

    // per-lane projection of own voxel (16 unique per wave, 4x redundant)
    int trow;
    {
        const float* cp = coords + (size_t)(voxG + l)*3;
        trow = b*MTOK + proj_idx(cp[0], cp[1], cp[2], Km, Rt);
    }

    // per-lane T row, contiguous 128 B at offset q*128
    const unsigned short* T = ws16 + OFF_T/2;
    uint4 tra[4][2];
    {
        const uint4* tp = (const uint4*)(T + (size_t)trow*HID + q*64);
        #pragma unroll
        for (int r = 0; r < 4; r++) {
            tra[r][0] = tp[r*2];
            tra[r][1] = tp[r*2 + 1];
        }
    }

    // W2^T A-frags hoisted to registers (32 VGPR), coalesced 8 B/lane
    const unsigned short* w2tG = ws16 + OFF_W2T/2;
    f16x4 w2t[16];
    #pragma unroll
    for (int nt = 0; nt < 16; nt++)
        w2t[nt] = *(const f16x4*)(w2tG + (nt*64 + lane)*4);

    __syncthreads();

    const f32x4 zero4 = {0.f,0.f,0.f,0.f};
    f32x4 acc2 = zero4;

    #pragma unroll
    for (int nt = 0; nt < 16; nt++) {
        bf16x8 wf0 = __builtin_bit_cast(bf16x8, w1aS[nt*64 + lane]);
        bf16x8 wf1 = __builtin_bit_cast(bf16x8, w1aS[(16 + nt)*64 + lane]);
        // C preloaded with T: Ct[r] = T[trow][nt*16 + q*4 + r]
        f32x4 Ct;
        #pragma unroll
        for (int r = 0; r < 4; r++) {
            unsigned dw = ((const unsigned*)&tra[r])[nt >> 1];
            Ct[r] = (nt & 1) ? __uint_as_float(dw & 0xFFFF0000u)
                             : __uint_as_float(dw << 16);
        }
        // FC1: D[hid nt*16+q*4+r][vox l] = W1a^T x vf + T
        f32x4 d1 = __builtin_amdgcn_mfma_f32_16x16x32_bf16(wf0, a1[0], Ct, 0, 0, 0);
        d1       = __builtin_amdgcn_mfma_f32_16x16x32_bf16(wf1, a1[1], d1, 0, 0, 0);
        // relu + cvt: h^T fragment is directly FC2's B-operand layout
        f16x4 hb;
        #pragma unroll
        for (int r = 0; r < 4; r++)
            hb[r] = (_Float16)fmaxf(d1[r], 0.0f);
        acc2 = __builtin_amdgcn_mfma_f32_16x16x16f16(w2t[nt], hb, acc2, 0, 0, 0);
    }

    // epilogue: D[out q*4+r][vox l]
    f32x4 bb = *(const f32x4*)(b2 + q*4);
    f32x4 o = acc2 + bb;
    *(f32x4*)(out + (size_t)(voxG + l)*OUTD + q*4) = o;
}

// ============================================================================
extern "C" void kernel_launch(void* const* d_in, const int* in_sizes, int n_in,
                              void* d_out, int out_size, void* d_ws, size_t ws_size,
                              hipStream_t stream)
{
    const float* patch  = (const float*)d_in[0];
    const float* vfeat  = (const float*)d_in[1];
    const float* coords = (const float*)d_in[2];
    const float* Km     = (const float*)d_in[3];
    const float* Rt     = (const float*)d_in[4];
    const float* W1     = (const float*)d_in[5];
    const float* b1     = (const float*)d_in[6];
    const float* W2     = (const float*)d_in[7];
    const float* b2     = (const float*)d_in[8];
    float* out          = (float*)d_out;
    unsigned short* ws16 = (unsigned short*)d_ws;

    const int prepBlocks = W1B_BLKS + W1A_BLKS + W2T_BLKS;   // 60
    prep_kernel<<<prepBlocks, 256, 0, stream>>>(W1, W2, ws16);
    t_gemm_kernel<<<T_BLKS, 256, 0, stream>>>(patch, ws16, b1, ws16);
    main_kernel<<<(BATCH*VOXPB)/64, 256, 0, stream>>>(vfeat, coords, Km, Rt,
                                                      ws16, b2, out);
}